// Round 1
// baseline (1215.454 us; speedup 1.0000x reference)
//
#include <hip/hip_runtime.h>

#define N_NODE 50000
#define N_EDGE 625000
#define DIM 128
#define NUM_REL 8
#define EPS 1e-6f

// ---------------------------------------------------------------------------
// Kernel 1: edge scatter.
// 32 threads per edge; each thread handles 4 consecutive feature dims
// (float4 gather of x[src], 4 f32 atomic adds into agg[dst]).
// Lane 0 of each edge-group also scatters the edge weight into the
// per-node per-relation weighted count table cnt[N_NODE][NUM_REL].
// ---------------------------------------------------------------------------
__global__ __launch_bounds__(256) void rgc_scatter(
    const float* __restrict__ x,
    const int*   __restrict__ node_in,
    const int*   __restrict__ node_out,
    const int*   __restrict__ relation,
    const float* __restrict__ ew,
    float*       __restrict__ agg,   // [N_NODE, DIM]  (aliases d_out)
    float*       __restrict__ cnt)   // [N_NODE, NUM_REL]
{
    int gid  = blockIdx.x * 256 + threadIdx.x;
    int e    = gid >> 5;          // edge index
    int lane = gid & 31;          // 0..31 -> dims [lane*4, lane*4+4)
    if (e >= N_EDGE) return;

    int   src = node_in[e];
    int   dst = node_out[e];
    float w   = ew[e];

    const float4* x4 = reinterpret_cast<const float4*>(x + (size_t)src * DIM);
    float4 v = x4[lane];

    float* o = agg + (size_t)dst * DIM + lane * 4;
    atomicAdd(o + 0, v.x * w);
    atomicAdd(o + 1, v.y * w);
    atomicAdd(o + 2, v.z * w);
    atomicAdd(o + 3, v.w * w);

    if (lane == 0) {
        atomicAdd(&cnt[(size_t)dst * NUM_REL + relation[e]], w);
    }
}

// ---------------------------------------------------------------------------
// Kernel 2: per-node finalize (in place on d_out).
//   y[n,j] = relu( (agg[n]@W[:,j] + deg_n*b[j] + sum_r cnt[n,r]*rel_emb[r,j])
//                  / (deg_n + EPS) )
// W (64 KB), b, rel_emb staged in LDS once per block; each block processes
// NPB nodes, 2 at a time (threads 0-127 -> node A dims, 128-255 -> node B).
// ---------------------------------------------------------------------------
__global__ __launch_bounds__(256) void rgc_finalize(
    const float* __restrict__ W,        // [DIM, DIM] row-major (k, j)
    const float* __restrict__ b,        // [DIM]
    const float* __restrict__ rel_emb,  // [NUM_REL, DIM]
    const float* __restrict__ cnt,      // [N_NODE, NUM_REL]
    float*       __restrict__ out,      // [N_NODE, DIM], holds agg on entry
    int nodes_per_block)
{
    __shared__ float Ws[DIM * DIM];
    __shared__ float bs[DIM];
    __shared__ float rs[NUM_REL * DIM];
    __shared__ float aggs[2][DIM];

    for (int i = threadIdx.x; i < DIM * DIM; i += 256) Ws[i] = W[i];
    for (int i = threadIdx.x; i < DIM; i += 256)       bs[i] = b[i];
    for (int i = threadIdx.x; i < NUM_REL * DIM; i += 256) rs[i] = rel_emb[i];

    const int half = threadIdx.x >> 7;   // 0 or 1
    const int j    = threadIdx.x & 127;  // output dim

    const int base = blockIdx.x * nodes_per_block;

    for (int nn = 0; nn < nodes_per_block; nn += 2) {
        const int n = base + nn + half;
        __syncthreads();  // protect aggs from previous iteration + W on iter 0
        if (n < N_NODE) aggs[half][j] = out[(size_t)n * DIM + j];
        __syncthreads();
        if (n < N_NODE) {
            float acc = 0.f;
            #pragma unroll 16
            for (int k = 0; k < DIM; ++k)
                acc += aggs[half][k] * Ws[k * DIM + j];

            float deg = 0.f, rb = 0.f;
            #pragma unroll
            for (int r = 0; r < NUM_REL; ++r) {
                float c = cnt[(size_t)n * NUM_REL + r];
                deg += c;
                rb  += c * rs[r * DIM + j];
            }
            float y = (acc + deg * bs[j] + rb) / (deg + EPS);
            out[(size_t)n * DIM + j] = fmaxf(y, 0.f);
        }
    }
}

extern "C" void kernel_launch(void* const* d_in, const int* in_sizes, int n_in,
                              void* d_out, int out_size, void* d_ws, size_t ws_size,
                              hipStream_t stream) {
    const float* x        = (const float*)d_in[0];
    const int*   node_in  = (const int*)  d_in[1];
    const int*   node_out = (const int*)  d_in[2];
    const int*   relation = (const int*)  d_in[3];
    const float* ew       = (const float*)d_in[4];
    const float* W        = (const float*)d_in[5];
    const float* b        = (const float*)d_in[6];
    const float* rel_emb  = (const float*)d_in[7];

    float* out = (float*)d_out;
    float* cnt = (float*)d_ws;   // N_NODE * NUM_REL floats = 1.6 MB

    // zero the accumulators (harness does not re-poison between replays)
    hipMemsetAsync(d_out, 0, (size_t)N_NODE * DIM * sizeof(float), stream);
    hipMemsetAsync(cnt,   0, (size_t)N_NODE * NUM_REL * sizeof(float), stream);

    // scatter: 32 threads/edge, 8 edges per 256-thread block
    dim3 g1((N_EDGE * 32 + 255) / 256);
    rgc_scatter<<<g1, 256, 0, stream>>>(x, node_in, node_out, relation, ew,
                                        out, cnt);

    // finalize: NPB nodes per block
    const int NPB = 16;
    dim3 g2((N_NODE + NPB - 1) / NPB);
    rgc_finalize<<<g2, 256, 0, stream>>>(W, b, rel_emb, cnt, out, NPB);
}

// Round 2
// 307.717 us; speedup vs baseline: 3.9499x; 3.9499x over previous
//
#include <hip/hip_runtime.h>

#define N_NODE 50000
#define N_EDGE 625000
#define DIM 128
#define NUM_REL 8
#define EPS 1e-6f
#define NPC 16   // nodes per chunk (fused kernel block)

// ===========================================================================
// CSR-build pipeline
// ===========================================================================

// K2: histogram of destination nodes
__global__ __launch_bounds__(256) void rgc_hist(
    const int* __restrict__ node_out, unsigned* __restrict__ hist)
{
    int e = blockIdx.x * 256 + threadIdx.x;
    if (e < N_EDGE) atomicAdd(&hist[node_out[e]], 1u);
}

// K3: single-block exclusive scan of hist -> offsets (and cursor copy)
__global__ __launch_bounds__(1024) void rgc_scan(
    const unsigned* __restrict__ hist,
    unsigned* __restrict__ offsets,   // [N_NODE+1]
    unsigned* __restrict__ cursor)    // [N_NODE]
{
    __shared__ unsigned lds[1024];
    const int t = threadIdx.x;
    const int C = (N_NODE + 1023) / 1024;  // 49

    unsigned s = 0;
    for (int c = 0; c < C; ++c) {
        int idx = t * C + c;
        if (idx < N_NODE) s += hist[idx];
    }
    lds[t] = s;
    // Hillis-Steele inclusive scan
    for (int off = 1; off < 1024; off <<= 1) {
        __syncthreads();
        unsigned v = (t >= off) ? lds[t - off] : 0u;
        __syncthreads();
        lds[t] += v;
    }
    __syncthreads();
    unsigned run = lds[t] - s;  // exclusive base for this thread's range
    for (int c = 0; c < C; ++c) {
        int idx = t * C + c;
        if (idx < N_NODE) {
            unsigned h = hist[idx];
            offsets[idx] = run;
            cursor[idx]  = run;
            run += h;
        }
    }
    if (t == 1023) offsets[N_NODE] = lds[1023];
}

// K4: scatter edges into CSR order. perm[pos] = (w, src | rel<<16)
__global__ __launch_bounds__(256) void rgc_permute(
    const int*   __restrict__ node_in,
    const int*   __restrict__ node_out,
    const int*   __restrict__ relation,
    const float* __restrict__ ew,
    unsigned*    __restrict__ cursor,
    float2*      __restrict__ perm)
{
    int e = blockIdx.x * 256 + threadIdx.x;
    if (e >= N_EDGE) return;
    int dst = node_out[e];
    unsigned pos = atomicAdd(&cursor[dst], 1u);
    unsigned pack = (unsigned)node_in[e] | ((unsigned)relation[e] << 16);
    perm[pos] = make_float2(ew[e], __uint_as_float(pack));
}

// ===========================================================================
// K5: fused segmented-sum + matmul + epilogue
//   per chunk of NPC nodes: 256 threads = 2 halves x 128 (j = tid&127)
//   half h handles nodes base + 2*ii + h, ii = 0..NPC/2-1
// ===========================================================================
__global__ __launch_bounds__(256) void rgc_fused(
    const float*    __restrict__ x,        // [N_NODE, DIM]
    const float*    __restrict__ W,        // [DIM, DIM] (k, j)
    const float*    __restrict__ b,        // [DIM]
    const float*    __restrict__ rel_emb,  // [NUM_REL, DIM]
    const unsigned* __restrict__ offsets,  // [N_NODE+1]
    const float2*   __restrict__ perm,     // [N_EDGE] (w, src|rel<<16)
    float*          __restrict__ out)      // [N_NODE, DIM]
{
    __shared__ float rel_lds[NUM_REL * DIM];   // 4 KB
    __shared__ float aggs[NPC][DIM];           // 8 KB

    const int tid = threadIdx.x;
    const int h   = tid >> 7;
    const int j   = tid & 127;

    for (int i = tid; i < NUM_REL * DIM; i += 256) rel_lds[i] = rel_emb[i];
    const float bj = b[j];
    __syncthreads();

    const int base = blockIdx.x * NPC;
    const int NH   = NPC / 2;

    float rb[NH], dg[NH];

    // ---- phase 1: segmented weighted gather-sum, ILP-4 over edges ----
    for (int ii = 0; ii < NH; ++ii) {
        const int n = base + ii * 2 + h;
        float acc = 0.f, rbv = 0.f, d = 0.f;
        int s = (int)offsets[n];
        int e = (int)offsets[n + 1];
        int i = s;
        for (; i + 4 <= e; i += 4) {
            float2 p0 = perm[i + 0];
            float2 p1 = perm[i + 1];
            float2 p2 = perm[i + 2];
            float2 p3 = perm[i + 3];
            unsigned b0 = __float_as_uint(p0.y);
            unsigned b1 = __float_as_uint(p1.y);
            unsigned b2 = __float_as_uint(p2.y);
            unsigned b3 = __float_as_uint(p3.y);
            float v0 = x[(size_t)(b0 & 0xFFFFu) * DIM + j];
            float v1 = x[(size_t)(b1 & 0xFFFFu) * DIM + j];
            float v2 = x[(size_t)(b2 & 0xFFFFu) * DIM + j];
            float v3 = x[(size_t)(b3 & 0xFFFFu) * DIM + j];
            acc += p0.x * v0;
            acc += p1.x * v1;
            acc += p2.x * v2;
            acc += p3.x * v3;
            rbv += p0.x * rel_lds[(b0 >> 16) * DIM + j];
            rbv += p1.x * rel_lds[(b1 >> 16) * DIM + j];
            rbv += p2.x * rel_lds[(b2 >> 16) * DIM + j];
            rbv += p3.x * rel_lds[(b3 >> 16) * DIM + j];
            d   += p0.x + p1.x + p2.x + p3.x;
        }
        for (; i < e; ++i) {
            float2 p = perm[i];
            unsigned bp = __float_as_uint(p.y);
            acc += p.x * x[(size_t)(bp & 0xFFFFu) * DIM + j];
            rbv += p.x * rel_lds[(bp >> 16) * DIM + j];
            d   += p.x;
        }
        aggs[ii * 2 + h][j] = acc;
        rb[ii] = rbv;
        dg[ii] = d;
    }
    __syncthreads();

    // ---- phase 2: 128x128 matmul, W from L2, 8-node register amortization ----
    float mm[NH];
    #pragma unroll
    for (int ii = 0; ii < NH; ++ii) mm[ii] = 0.f;

    #pragma unroll 4
    for (int k = 0; k < DIM; ++k) {
        float wv = W[k * DIM + j];
        #pragma unroll
        for (int ii = 0; ii < NH; ++ii)
            mm[ii] += aggs[ii * 2 + h][k] * wv;
    }

    // ---- epilogue ----
    for (int ii = 0; ii < NH; ++ii) {
        const int n = base + ii * 2 + h;
        float y = (mm[ii] + dg[ii] * bj + rb[ii]) / (dg[ii] + EPS);
        out[(size_t)n * DIM + j] = fmaxf(y, 0.f);
    }
}

// ===========================================================================
// Fallback path (old atomic scatter) in case ws_size is too small
// ===========================================================================
__global__ __launch_bounds__(256) void rgc_scatter(
    const float* __restrict__ x,
    const int*   __restrict__ node_in,
    const int*   __restrict__ node_out,
    const int*   __restrict__ relation,
    const float* __restrict__ ew,
    float*       __restrict__ agg,
    float*       __restrict__ cnt)
{
    int gid  = blockIdx.x * 256 + threadIdx.x;
    int e    = gid >> 5;
    int lane = gid & 31;
    if (e >= N_EDGE) return;
    int   src = node_in[e];
    int   dst = node_out[e];
    float w   = ew[e];
    const float4* x4 = reinterpret_cast<const float4*>(x + (size_t)src * DIM);
    float4 v = x4[lane];
    float* o = agg + (size_t)dst * DIM + lane * 4;
    atomicAdd(o + 0, v.x * w);
    atomicAdd(o + 1, v.y * w);
    atomicAdd(o + 2, v.z * w);
    atomicAdd(o + 3, v.w * w);
    if (lane == 0) atomicAdd(&cnt[(size_t)dst * NUM_REL + relation[e]], w);
}

__global__ __launch_bounds__(256) void rgc_finalize(
    const float* __restrict__ W,
    const float* __restrict__ b,
    const float* __restrict__ rel_emb,
    const float* __restrict__ cnt,
    float*       __restrict__ out,
    int nodes_per_block)
{
    __shared__ float Ws[DIM * DIM];
    __shared__ float bs[DIM];
    __shared__ float rs[NUM_REL * DIM];
    __shared__ float aggs2[2][DIM];
    for (int i = threadIdx.x; i < DIM * DIM; i += 256) Ws[i] = W[i];
    for (int i = threadIdx.x; i < DIM; i += 256)       bs[i] = b[i];
    for (int i = threadIdx.x; i < NUM_REL * DIM; i += 256) rs[i] = rel_emb[i];
    const int half = threadIdx.x >> 7;
    const int j    = threadIdx.x & 127;
    const int base = blockIdx.x * nodes_per_block;
    for (int nn = 0; nn < nodes_per_block; nn += 2) {
        const int n = base + nn + half;
        __syncthreads();
        if (n < N_NODE) aggs2[half][j] = out[(size_t)n * DIM + j];
        __syncthreads();
        if (n < N_NODE) {
            float acc = 0.f;
            #pragma unroll 16
            for (int k = 0; k < DIM; ++k)
                acc += aggs2[half][k] * Ws[k * DIM + j];
            float deg = 0.f, rbv = 0.f;
            #pragma unroll
            for (int r = 0; r < NUM_REL; ++r) {
                float c = cnt[(size_t)n * NUM_REL + r];
                deg += c;
                rbv += c * rs[r * DIM + j];
            }
            float y = (acc + deg * bs[j] + rbv) / (deg + EPS);
            out[(size_t)n * DIM + j] = fmaxf(y, 0.f);
        }
    }
}

// ===========================================================================
extern "C" void kernel_launch(void* const* d_in, const int* in_sizes, int n_in,
                              void* d_out, int out_size, void* d_ws, size_t ws_size,
                              hipStream_t stream) {
    const float* x        = (const float*)d_in[0];
    const int*   node_in  = (const int*)  d_in[1];
    const int*   node_out = (const int*)  d_in[2];
    const int*   relation = (const int*)  d_in[3];
    const float* ew       = (const float*)d_in[4];
    const float* W        = (const float*)d_in[5];
    const float* b        = (const float*)d_in[6];
    const float* rel_emb  = (const float*)d_in[7];
    float* out = (float*)d_out;

    // ws layout
    const size_t OFF_HIST   = 0;                       // u32[N_NODE]      200000 B
    const size_t OFF_CURSOR = 200000;                  // u32[N_NODE]      200000 B
    const size_t OFF_OFFS   = 400000;                  // u32[N_NODE+1]    200004 B
    const size_t OFF_PERM   = 600064;                  // float2[N_EDGE]   5 MB
    const size_t WS_NEEDED  = OFF_PERM + (size_t)N_EDGE * sizeof(float2);

    if (ws_size < WS_NEEDED) {
        // fallback: old atomic path (needs 1.6 MB)
        float* cnt = (float*)d_ws;
        hipMemsetAsync(d_out, 0, (size_t)N_NODE * DIM * sizeof(float), stream);
        hipMemsetAsync(cnt,   0, (size_t)N_NODE * NUM_REL * sizeof(float), stream);
        dim3 g1((N_EDGE * 32 + 255) / 256);
        rgc_scatter<<<g1, 256, 0, stream>>>(x, node_in, node_out, relation, ew, out, cnt);
        const int NPB = 16;
        dim3 g2((N_NODE + NPB - 1) / NPB);
        rgc_finalize<<<g2, 256, 0, stream>>>(W, b, rel_emb, cnt, out, NPB);
        return;
    }

    unsigned* hist    = (unsigned*)((char*)d_ws + OFF_HIST);
    unsigned* cursor  = (unsigned*)((char*)d_ws + OFF_CURSOR);
    unsigned* offsets = (unsigned*)((char*)d_ws + OFF_OFFS);
    float2*   perm    = (float2*)  ((char*)d_ws + OFF_PERM);

    hipMemsetAsync(hist, 0, (size_t)N_NODE * sizeof(unsigned), stream);

    dim3 ge((N_EDGE + 255) / 256);
    rgc_hist<<<ge, 256, 0, stream>>>(node_out, hist);
    rgc_scan<<<1, 1024, 0, stream>>>(hist, offsets, cursor);
    rgc_permute<<<ge, 256, 0, stream>>>(node_in, node_out, relation, ew, cursor, perm);

    dim3 gf(N_NODE / NPC);   // 50000/16 = 3125 exactly
    rgc_fused<<<gf, 256, 0, stream>>>(x, W, b, rel_emb, offsets, perm, out);
}

// Round 3
// 190.573 us; speedup vs baseline: 6.3779x; 1.6147x over previous
//
#include <hip/hip_runtime.h>

#define N_NODE 50000
#define N_EDGE 625000
#define DIM 128
#define NUM_REL 8
#define EPS 1e-6f
#define NPC 16                                  // nodes per chunk (fused kernel)
#define SCAN_TILES ((N_NODE + 255) / 256)       // 196

// ===========================================================================
// CSR-build pipeline
// ===========================================================================

// K1: histogram of destination nodes
__global__ __launch_bounds__(256) void rgc_hist(
    const int* __restrict__ node_out, unsigned* __restrict__ hist)
{
    int e = blockIdx.x * 256 + threadIdx.x;
    if (e < N_EDGE) atomicAdd(&hist[node_out[e]], 1u);
}

// K2a: per-tile (256-element) sums of hist
__global__ __launch_bounds__(256) void rgc_scan1(
    const unsigned* __restrict__ hist, unsigned* __restrict__ partial)
{
    int idx = blockIdx.x * 256 + threadIdx.x;
    unsigned v = (idx < N_NODE) ? hist[idx] : 0u;
    #pragma unroll
    for (int o = 32; o > 0; o >>= 1) v += __shfl_down(v, o, 64);
    __shared__ unsigned ws[4];
    if ((threadIdx.x & 63) == 0) ws[threadIdx.x >> 6] = v;
    __syncthreads();
    if (threadIdx.x == 0) partial[blockIdx.x] = ws[0] + ws[1] + ws[2] + ws[3];
}

// K2b: exclusive scan of the 196 tile sums (in place), single small block
__global__ __launch_bounds__(256) void rgc_scan2(unsigned* __restrict__ partial)
{
    __shared__ unsigned lds[256];
    int t = threadIdx.x;
    unsigned v = (t < SCAN_TILES) ? partial[t] : 0u;
    lds[t] = v;
    for (int off = 1; off < 256; off <<= 1) {
        __syncthreads();
        unsigned u = (t >= off) ? lds[t - off] : 0u;
        __syncthreads();
        lds[t] += u;
    }
    __syncthreads();
    if (t < SCAN_TILES) partial[t] = lds[t] - v;   // exclusive
}

// K2c: per-tile exclusive scan + tile base -> offsets, cursor
__global__ __launch_bounds__(256) void rgc_scan3(
    const unsigned* __restrict__ hist, const unsigned* __restrict__ partial,
    unsigned* __restrict__ offsets, unsigned* __restrict__ cursor)
{
    __shared__ unsigned lds[256];
    int t = threadIdx.x;
    int idx = blockIdx.x * 256 + t;
    unsigned v = (idx < N_NODE) ? hist[idx] : 0u;
    lds[t] = v;
    for (int off = 1; off < 256; off <<= 1) {
        __syncthreads();
        unsigned u = (t >= off) ? lds[t - off] : 0u;
        __syncthreads();
        lds[t] += u;
    }
    __syncthreads();
    unsigned e = partial[blockIdx.x] + lds[t] - v;  // global exclusive prefix
    if (idx < N_NODE) { offsets[idx] = e; cursor[idx] = e; }
    if (idx == 0) offsets[N_NODE] = N_EDGE;         // total is a known constant
}

// K3: scatter edges into CSR order. perm[pos] = (w, src | rel<<16)
__global__ __launch_bounds__(256) void rgc_permute(
    const int*   __restrict__ node_in,
    const int*   __restrict__ node_out,
    const int*   __restrict__ relation,
    const float* __restrict__ ew,
    unsigned*    __restrict__ cursor,
    float2*      __restrict__ perm)
{
    int e = blockIdx.x * 256 + threadIdx.x;
    if (e >= N_EDGE) return;
    int dst = node_out[e];
    unsigned pos = atomicAdd(&cursor[dst], 1u);
    unsigned pack = (unsigned)node_in[e] | ((unsigned)relation[e] << 16);
    perm[pos] = make_float2(ew[e], __uint_as_float(pack));
}

// ===========================================================================
// K4: fused segmented-sum + matmul + epilogue
//   per chunk of NPC nodes: 256 threads = 2 halves x 128 (j = tid&127)
//   half h handles nodes base + 2*ii + h, ii = 0..NPC/2-1
// ===========================================================================
__global__ __launch_bounds__(256) void rgc_fused(
    const float*    __restrict__ x,        // [N_NODE, DIM]
    const float*    __restrict__ W,        // [DIM, DIM] (k, j)
    const float*    __restrict__ b,        // [DIM]
    const float*    __restrict__ rel_emb,  // [NUM_REL, DIM]
    const unsigned* __restrict__ offsets,  // [N_NODE+1]
    const float2*   __restrict__ perm,     // [N_EDGE] (w, src|rel<<16)
    float*          __restrict__ out)      // [N_NODE, DIM]
{
    __shared__ float rel_lds[NUM_REL * DIM];   // 4 KB
    __shared__ float aggs[NPC][DIM];           // 8 KB

    const int tid = threadIdx.x;
    const int h   = tid >> 7;
    const int j   = tid & 127;

    for (int i = tid; i < NUM_REL * DIM; i += 256) rel_lds[i] = rel_emb[i];
    const float bj = b[j];
    __syncthreads();

    const int base = blockIdx.x * NPC;
    const int NH   = NPC / 2;

    float rb[NH], dg[NH];

    // ---- phase 1: segmented weighted gather-sum, ILP-4 over edges ----
    for (int ii = 0; ii < NH; ++ii) {
        const int n = base + ii * 2 + h;
        float acc = 0.f, rbv = 0.f, d = 0.f;
        int s = (int)offsets[n];
        int e = (int)offsets[n + 1];
        int i = s;
        for (; i + 4 <= e; i += 4) {
            float2 p0 = perm[i + 0];
            float2 p1 = perm[i + 1];
            float2 p2 = perm[i + 2];
            float2 p3 = perm[i + 3];
            unsigned b0 = __float_as_uint(p0.y);
            unsigned b1 = __float_as_uint(p1.y);
            unsigned b2 = __float_as_uint(p2.y);
            unsigned b3 = __float_as_uint(p3.y);
            float v0 = x[(size_t)(b0 & 0xFFFFu) * DIM + j];
            float v1 = x[(size_t)(b1 & 0xFFFFu) * DIM + j];
            float v2 = x[(size_t)(b2 & 0xFFFFu) * DIM + j];
            float v3 = x[(size_t)(b3 & 0xFFFFu) * DIM + j];
            acc += p0.x * v0;
            acc += p1.x * v1;
            acc += p2.x * v2;
            acc += p3.x * v3;
            rbv += p0.x * rel_lds[(b0 >> 16) * DIM + j];
            rbv += p1.x * rel_lds[(b1 >> 16) * DIM + j];
            rbv += p2.x * rel_lds[(b2 >> 16) * DIM + j];
            rbv += p3.x * rel_lds[(b3 >> 16) * DIM + j];
            d   += p0.x + p1.x + p2.x + p3.x;
        }
        for (; i < e; ++i) {
            float2 p = perm[i];
            unsigned bp = __float_as_uint(p.y);
            acc += p.x * x[(size_t)(bp & 0xFFFFu) * DIM + j];
            rbv += p.x * rel_lds[(bp >> 16) * DIM + j];
            d   += p.x;
        }
        aggs[ii * 2 + h][j] = acc;
        rb[ii] = rbv;
        dg[ii] = d;
    }
    __syncthreads();

    // ---- phase 2: 128x128 matmul, W from L2, 8-node register amortization ----
    float mm[NH];
    #pragma unroll
    for (int ii = 0; ii < NH; ++ii) mm[ii] = 0.f;

    #pragma unroll 4
    for (int k = 0; k < DIM; ++k) {
        float wv = W[k * DIM + j];
        #pragma unroll
        for (int ii = 0; ii < NH; ++ii)
            mm[ii] += aggs[ii * 2 + h][k] * wv;
    }

    // ---- epilogue ----
    for (int ii = 0; ii < NH; ++ii) {
        const int n = base + ii * 2 + h;
        float y = (mm[ii] + dg[ii] * bj + rb[ii]) / (dg[ii] + EPS);
        out[(size_t)n * DIM + j] = fmaxf(y, 0.f);
    }
}

// ===========================================================================
// Fallback path (old atomic scatter) in case ws_size is too small
// ===========================================================================
__global__ __launch_bounds__(256) void rgc_scatter(
    const float* __restrict__ x,
    const int*   __restrict__ node_in,
    const int*   __restrict__ node_out,
    const int*   __restrict__ relation,
    const float* __restrict__ ew,
    float*       __restrict__ agg,
    float*       __restrict__ cnt)
{
    int gid  = blockIdx.x * 256 + threadIdx.x;
    int e    = gid >> 5;
    int lane = gid & 31;
    if (e >= N_EDGE) return;
    int   src = node_in[e];
    int   dst = node_out[e];
    float w   = ew[e];
    const float4* x4 = reinterpret_cast<const float4*>(x + (size_t)src * DIM);
    float4 v = x4[lane];
    float* o = agg + (size_t)dst * DIM + lane * 4;
    atomicAdd(o + 0, v.x * w);
    atomicAdd(o + 1, v.y * w);
    atomicAdd(o + 2, v.z * w);
    atomicAdd(o + 3, v.w * w);
    if (lane == 0) atomicAdd(&cnt[(size_t)dst * NUM_REL + relation[e]], w);
}

__global__ __launch_bounds__(256) void rgc_finalize(
    const float* __restrict__ W,
    const float* __restrict__ b,
    const float* __restrict__ rel_emb,
    const float* __restrict__ cnt,
    float*       __restrict__ out,
    int nodes_per_block)
{
    __shared__ float Ws[DIM * DIM];
    __shared__ float bs[DIM];
    __shared__ float rs[NUM_REL * DIM];
    __shared__ float aggs2[2][DIM];
    for (int i = threadIdx.x; i < DIM * DIM; i += 256) Ws[i] = W[i];
    for (int i = threadIdx.x; i < DIM; i += 256)       bs[i] = b[i];
    for (int i = threadIdx.x; i < NUM_REL * DIM; i += 256) rs[i] = rel_emb[i];
    const int half = threadIdx.x >> 7;
    const int j    = threadIdx.x & 127;
    const int base = blockIdx.x * nodes_per_block;
    for (int nn = 0; nn < nodes_per_block; nn += 2) {
        const int n = base + nn + half;
        __syncthreads();
        if (n < N_NODE) aggs2[half][j] = out[(size_t)n * DIM + j];
        __syncthreads();
        if (n < N_NODE) {
            float acc = 0.f;
            #pragma unroll 16
            for (int k = 0; k < DIM; ++k)
                acc += aggs2[half][k] * Ws[k * DIM + j];
            float deg = 0.f, rbv = 0.f;
            #pragma unroll
            for (int r = 0; r < NUM_REL; ++r) {
                float c = cnt[(size_t)n * NUM_REL + r];
                deg += c;
                rbv += c * rs[r * DIM + j];
            }
            float y = (acc + deg * bs[j] + rbv) / (deg + EPS);
            out[(size_t)n * DIM + j] = fmaxf(y, 0.f);
        }
    }
}

// ===========================================================================
extern "C" void kernel_launch(void* const* d_in, const int* in_sizes, int n_in,
                              void* d_out, int out_size, void* d_ws, size_t ws_size,
                              hipStream_t stream) {
    const float* x        = (const float*)d_in[0];
    const int*   node_in  = (const int*)  d_in[1];
    const int*   node_out = (const int*)  d_in[2];
    const int*   relation = (const int*)  d_in[3];
    const float* ew       = (const float*)d_in[4];
    const float* W        = (const float*)d_in[5];
    const float* b        = (const float*)d_in[6];
    const float* rel_emb  = (const float*)d_in[7];
    float* out = (float*)d_out;

    // ws layout
    const size_t OFF_HIST   = 0;                       // u32[N_NODE]      200000 B
    const size_t OFF_CURSOR = 200000;                  // u32[N_NODE]      200000 B
    const size_t OFF_OFFS   = 400000;                  // u32[N_NODE+1]    200004 B
    const size_t OFF_PART   = 600064;                  // u32[SCAN_TILES]  784 B
    const size_t OFF_PERM   = 601088;                  // float2[N_EDGE]   5 MB
    const size_t WS_NEEDED  = OFF_PERM + (size_t)N_EDGE * sizeof(float2);

    if (ws_size < WS_NEEDED) {
        // fallback: old atomic path (needs 1.6 MB)
        float* cnt = (float*)d_ws;
        hipMemsetAsync(d_out, 0, (size_t)N_NODE * DIM * sizeof(float), stream);
        hipMemsetAsync(cnt,   0, (size_t)N_NODE * NUM_REL * sizeof(float), stream);
        dim3 g1((N_EDGE * 32 + 255) / 256);
        rgc_scatter<<<g1, 256, 0, stream>>>(x, node_in, node_out, relation, ew, out, cnt);
        const int NPB = 16;
        dim3 g2((N_NODE + NPB - 1) / NPB);
        rgc_finalize<<<g2, 256, 0, stream>>>(W, b, rel_emb, cnt, out, NPB);
        return;
    }

    unsigned* hist    = (unsigned*)((char*)d_ws + OFF_HIST);
    unsigned* cursor  = (unsigned*)((char*)d_ws + OFF_CURSOR);
    unsigned* offsets = (unsigned*)((char*)d_ws + OFF_OFFS);
    unsigned* partial = (unsigned*)((char*)d_ws + OFF_PART);
    float2*   perm    = (float2*)  ((char*)d_ws + OFF_PERM);

    hipMemsetAsync(hist, 0, (size_t)N_NODE * sizeof(unsigned), stream);

    dim3 ge((N_EDGE + 255) / 256);
    rgc_hist<<<ge, 256, 0, stream>>>(node_out, hist);
    rgc_scan1<<<SCAN_TILES, 256, 0, stream>>>(hist, partial);
    rgc_scan2<<<1, 256, 0, stream>>>(partial);
    rgc_scan3<<<SCAN_TILES, 256, 0, stream>>>(hist, partial, offsets, cursor);
    rgc_permute<<<ge, 256, 0, stream>>>(node_in, node_out, relation, ew, cursor, perm);

    dim3 gf(N_NODE / NPC);   // 50000/16 = 3125 exactly
    rgc_fused<<<gf, 256, 0, stream>>>(x, W, b, rel_emb, offsets, perm, out);
}

// Round 4
// 167.555 us; speedup vs baseline: 7.2541x; 1.1374x over previous
//
#include <hip/hip_runtime.h>

#define N_NODE 50000
#define N_EDGE 625000
#define DIM 128
#define NUM_REL 8
#define EPS 1e-6f
#define NPC 32                                  // nodes per chunk (fused kernel)
#define SCAN_TILES ((N_NODE + 255) / 256)       // 196

// ===========================================================================
// CSR-build pipeline
// ===========================================================================

// K1: histogram of destination nodes
__global__ __launch_bounds__(256) void rgc_hist(
    const int* __restrict__ node_out, unsigned* __restrict__ hist)
{
    int e = blockIdx.x * 256 + threadIdx.x;
    if (e < N_EDGE) atomicAdd(&hist[node_out[e]], 1u);
}

// K2a: per-tile (256-element) sums of hist
__global__ __launch_bounds__(256) void rgc_scan1(
    const unsigned* __restrict__ hist, unsigned* __restrict__ partial)
{
    int idx = blockIdx.x * 256 + threadIdx.x;
    unsigned v = (idx < N_NODE) ? hist[idx] : 0u;
    #pragma unroll
    for (int o = 32; o > 0; o >>= 1) v += __shfl_down(v, o, 64);
    __shared__ unsigned ws[4];
    if ((threadIdx.x & 63) == 0) ws[threadIdx.x >> 6] = v;
    __syncthreads();
    if (threadIdx.x == 0) partial[blockIdx.x] = ws[0] + ws[1] + ws[2] + ws[3];
}

// K2b: per-tile exclusive scan; tile base computed in-block from partials
__global__ __launch_bounds__(256) void rgc_scan3(
    const unsigned* __restrict__ hist, const unsigned* __restrict__ partial,
    unsigned* __restrict__ offsets, unsigned* __restrict__ cursor)
{
    __shared__ unsigned lds[256];
    __shared__ unsigned wred[4];
    __shared__ unsigned base_sh;
    const int t   = threadIdx.x;
    const int blk = blockIdx.x;

    // base = sum of partial[0..blk)   (blk <= 195, so t < blk < SCAN_TILES)
    unsigned pv = (t < blk) ? partial[t] : 0u;
    #pragma unroll
    for (int o = 32; o > 0; o >>= 1) pv += __shfl_down(pv, o, 64);
    if ((t & 63) == 0) wred[t >> 6] = pv;
    __syncthreads();
    if (t == 0) base_sh = wred[0] + wred[1] + wred[2] + wred[3];

    int idx = blk * 256 + t;
    unsigned v = (idx < N_NODE) ? hist[idx] : 0u;
    lds[t] = v;
    for (int off = 1; off < 256; off <<= 1) {
        __syncthreads();
        unsigned u = (t >= off) ? lds[t - off] : 0u;
        __syncthreads();
        lds[t] += u;
    }
    __syncthreads();
    unsigned pos = base_sh + lds[t] - v;   // global exclusive prefix
    if (idx < N_NODE) { offsets[idx] = pos; cursor[idx] = pos; }
    if (idx == 0) offsets[N_NODE] = N_EDGE;
}

// K3: scatter edges into CSR order.
// perm[pos] = (w, pack) where pack = rel<<26 | (src*512B)  (src byte offset)
__global__ __launch_bounds__(256) void rgc_permute(
    const int*   __restrict__ node_in,
    const int*   __restrict__ node_out,
    const int*   __restrict__ relation,
    const float* __restrict__ ew,
    unsigned*    __restrict__ cursor,
    float2*      __restrict__ perm)
{
    int e = blockIdx.x * 256 + threadIdx.x;
    if (e >= N_EDGE) return;
    int dst = node_out[e];
    unsigned pos = atomicAdd(&cursor[dst], 1u);
    unsigned pack = ((unsigned)relation[e] << 26) | ((unsigned)node_in[e] << 9);
    perm[pos] = make_float2(ew[e], __uint_as_float(pack));
}

// ===========================================================================
// K4: fused segmented-sum + matmul + epilogue
//   256 threads = 4 waves; wave = slot; lane j2 = tid&63 owns dims {2*j2, 2*j2+1}
//   phase 1: slot processes NPC/4=8 nodes serially, float2 gathers
//   phase 2: group g (=wave) computes 8 nodes' matmul rows, b128 agg broadcasts
// ===========================================================================
__global__ __launch_bounds__(256) void rgc_fused(
    const float*    __restrict__ x,        // [N_NODE, DIM]
    const float*    __restrict__ W,        // [DIM, DIM] (k, j)
    const float*    __restrict__ b,        // [DIM]
    const float*    __restrict__ rel_emb,  // [NUM_REL, DIM]
    const unsigned* __restrict__ offsets,  // [N_NODE+1]
    const float2*   __restrict__ perm,     // [N_EDGE]
    float*          __restrict__ out)      // [N_NODE, DIM]
{
    __shared__ float rel_lds[NUM_REL * DIM];   // 4 KB
    __shared__ float aggs[NPC][DIM];           // 16 KB
    __shared__ float cnts[NPC][NUM_REL];       // 1 KB

    const int tid  = threadIdx.x;
    const int j2   = tid & 63;
    const int slot = tid >> 6;
    const unsigned jo = (unsigned)(j2 * 8);    // lane byte offset within a row

    for (int i = tid; i < NUM_REL * DIM; i += 256) rel_lds[i] = rel_emb[i];
    cnts[tid >> 3][tid & 7] = 0.f;             // 256 slots exactly
    __syncthreads();

    const int  base  = blockIdx.x * NPC;
    const bool lane0 = (j2 == 0);
    const char* xb   = (const char*)x;

    // ---- phase 1: per-node weighted gather-sum (1 wave per node) ----
    for (int q = 0; q < NPC / 4; ++q) {
        const int l = slot * (NPC / 4) + q;
        const int n = base + l;
        float2 acc = make_float2(0.f, 0.f);
        if (n < N_NODE) {
            int s = (int)offsets[n];
            int e = (int)offsets[n + 1];
            s = __builtin_amdgcn_readfirstlane(s);
            e = __builtin_amdgcn_readfirstlane(e);
            int i = s;
            for (; i + 4 <= e; i += 4) {
                float2 p0 = perm[i + 0];
                float2 p1 = perm[i + 1];
                float2 p2 = perm[i + 2];
                float2 p3 = perm[i + 3];
                unsigned k0 = __float_as_uint(p0.y);
                unsigned k1 = __float_as_uint(p1.y);
                unsigned k2 = __float_as_uint(p2.y);
                unsigned k3 = __float_as_uint(p3.y);
                float2 v0 = *(const float2*)(xb + ((k0 & 0x01FFFE00u) + jo));
                float2 v1 = *(const float2*)(xb + ((k1 & 0x01FFFE00u) + jo));
                float2 v2 = *(const float2*)(xb + ((k2 & 0x01FFFE00u) + jo));
                float2 v3 = *(const float2*)(xb + ((k3 & 0x01FFFE00u) + jo));
                acc.x += p0.x * v0.x; acc.y += p0.x * v0.y;
                acc.x += p1.x * v1.x; acc.y += p1.x * v1.y;
                acc.x += p2.x * v2.x; acc.y += p2.x * v2.y;
                acc.x += p3.x * v3.x; acc.y += p3.x * v3.y;
                if (lane0) {
                    atomicAdd(&cnts[l][k0 >> 26], p0.x);
                    atomicAdd(&cnts[l][k1 >> 26], p1.x);
                    atomicAdd(&cnts[l][k2 >> 26], p2.x);
                    atomicAdd(&cnts[l][k3 >> 26], p3.x);
                }
            }
            for (; i < e; ++i) {
                float2 p = perm[i];
                unsigned kk = __float_as_uint(p.y);
                float2 v = *(const float2*)(xb + ((kk & 0x01FFFE00u) + jo));
                acc.x += p.x * v.x; acc.y += p.x * v.y;
                if (lane0) atomicAdd(&cnts[l][kk >> 26], p.x);
            }
        }
        *(float2*)&aggs[l][j2 * 2] = acc;   // zeros for out-of-range nodes
    }
    __syncthreads();

    // ---- phase 2: [8 nodes x 128] @ [128 x 128] per wave ----
    const int g = slot;
    float2 mm[8];
    #pragma unroll
    for (int m = 0; m < 8; ++m) mm[m] = make_float2(0.f, 0.f);

    for (int k = 0; k < DIM; k += 4) {
        const float2 wv0 = *(const float2*)&W[(k + 0) * DIM + j2 * 2];
        const float2 wv1 = *(const float2*)&W[(k + 1) * DIM + j2 * 2];
        const float2 wv2 = *(const float2*)&W[(k + 2) * DIM + j2 * 2];
        const float2 wv3 = *(const float2*)&W[(k + 3) * DIM + j2 * 2];
        #pragma unroll
        for (int m = 0; m < 8; ++m) {
            const float4 av = *(const float4*)&aggs[g * 8 + m][k];
            mm[m].x += av.x * wv0.x; mm[m].y += av.x * wv0.y;
            mm[m].x += av.y * wv1.x; mm[m].y += av.y * wv1.y;
            mm[m].x += av.z * wv2.x; mm[m].y += av.z * wv2.y;
            mm[m].x += av.w * wv3.x; mm[m].y += av.w * wv3.y;
        }
    }

    // ---- epilogue ----
    const float2 bv = *(const float2*)&b[j2 * 2];
    float2 rv[NUM_REL];
    #pragma unroll
    for (int r = 0; r < NUM_REL; ++r)
        rv[r] = *(const float2*)&rel_lds[r * DIM + j2 * 2];

    #pragma unroll
    for (int m = 0; m < 8; ++m) {
        const int l = g * 8 + m;
        const int n = base + l;
        if (n < N_NODE) {
            float dg = 0.f, rbx = 0.f, rby = 0.f;
            #pragma unroll
            for (int r = 0; r < NUM_REL; ++r) {
                const float c = cnts[l][r];
                dg  += c;
                rbx += c * rv[r].x;
                rby += c * rv[r].y;
            }
            const float inv = 1.0f / (dg + EPS);
            float yx = (mm[m].x + dg * bv.x + rbx) * inv;
            float yy = (mm[m].y + dg * bv.y + rby) * inv;
            *(float2*)&out[(size_t)n * DIM + j2 * 2] =
                make_float2(fmaxf(yx, 0.f), fmaxf(yy, 0.f));
        }
    }
}

// ===========================================================================
// Fallback path (old atomic scatter) in case ws_size is too small
// ===========================================================================
__global__ __launch_bounds__(256) void rgc_scatter(
    const float* __restrict__ x,
    const int*   __restrict__ node_in,
    const int*   __restrict__ node_out,
    const int*   __restrict__ relation,
    const float* __restrict__ ew,
    float*       __restrict__ agg,
    float*       __restrict__ cnt)
{
    int gid  = blockIdx.x * 256 + threadIdx.x;
    int e    = gid >> 5;
    int lane = gid & 31;
    if (e >= N_EDGE) return;
    int   src = node_in[e];
    int   dst = node_out[e];
    float w   = ew[e];
    const float4* x4 = reinterpret_cast<const float4*>(x + (size_t)src * DIM);
    float4 v = x4[lane];
    float* o = agg + (size_t)dst * DIM + lane * 4;
    atomicAdd(o + 0, v.x * w);
    atomicAdd(o + 1, v.y * w);
    atomicAdd(o + 2, v.z * w);
    atomicAdd(o + 3, v.w * w);
    if (lane == 0) atomicAdd(&cnt[(size_t)dst * NUM_REL + relation[e]], w);
}

__global__ __launch_bounds__(256) void rgc_finalize(
    const float* __restrict__ W,
    const float* __restrict__ b,
    const float* __restrict__ rel_emb,
    const float* __restrict__ cnt,
    float*       __restrict__ out,
    int nodes_per_block)
{
    __shared__ float Ws[DIM * DIM];
    __shared__ float bs[DIM];
    __shared__ float rs[NUM_REL * DIM];
    __shared__ float aggs2[2][DIM];
    for (int i = threadIdx.x; i < DIM * DIM; i += 256) Ws[i] = W[i];
    for (int i = threadIdx.x; i < DIM; i += 256)       bs[i] = b[i];
    for (int i = threadIdx.x; i < NUM_REL * DIM; i += 256) rs[i] = rel_emb[i];
    const int half = threadIdx.x >> 7;
    const int j    = threadIdx.x & 127;
    const int base = blockIdx.x * nodes_per_block;
    for (int nn = 0; nn < nodes_per_block; nn += 2) {
        const int n = base + nn + half;
        __syncthreads();
        if (n < N_NODE) aggs2[half][j] = out[(size_t)n * DIM + j];
        __syncthreads();
        if (n < N_NODE) {
            float acc = 0.f;
            #pragma unroll 16
            for (int k = 0; k < DIM; ++k)
                acc += aggs2[half][k] * Ws[k * DIM + j];
            float deg = 0.f, rbv = 0.f;
            #pragma unroll
            for (int r = 0; r < NUM_REL; ++r) {
                float c = cnt[(size_t)n * NUM_REL + r];
                deg += c;
                rbv += c * rs[r * DIM + j];
            }
            float y = (acc + deg * bs[j] + rbv) / (deg + EPS);
            out[(size_t)n * DIM + j] = fmaxf(y, 0.f);
        }
    }
}

// ===========================================================================
extern "C" void kernel_launch(void* const* d_in, const int* in_sizes, int n_in,
                              void* d_out, int out_size, void* d_ws, size_t ws_size,
                              hipStream_t stream) {
    const float* x        = (const float*)d_in[0];
    const int*   node_in  = (const int*)  d_in[1];
    const int*   node_out = (const int*)  d_in[2];
    const int*   relation = (const int*)  d_in[3];
    const float* ew       = (const float*)d_in[4];
    const float* W        = (const float*)d_in[5];
    const float* b        = (const float*)d_in[6];
    const float* rel_emb  = (const float*)d_in[7];
    float* out = (float*)d_out;

    // ws layout
    const size_t OFF_HIST   = 0;                       // u32[N_NODE]      200000 B
    const size_t OFF_CURSOR = 200000;                  // u32[N_NODE]      200000 B
    const size_t OFF_OFFS   = 400000;                  // u32[N_NODE+1]    200004 B
    const size_t OFF_PART   = 600064;                  // u32[SCAN_TILES]  784 B
    const size_t OFF_PERM   = 601088;                  // float2[N_EDGE]   5 MB
    const size_t WS_NEEDED  = OFF_PERM + (size_t)N_EDGE * sizeof(float2);

    if (ws_size < WS_NEEDED) {
        // fallback: atomic path (needs 1.6 MB)
        float* cnt = (float*)d_ws;
        hipMemsetAsync(d_out, 0, (size_t)N_NODE * DIM * sizeof(float), stream);
        hipMemsetAsync(cnt,   0, (size_t)N_NODE * NUM_REL * sizeof(float), stream);
        dim3 g1((N_EDGE * 32 + 255) / 256);
        rgc_scatter<<<g1, 256, 0, stream>>>(x, node_in, node_out, relation, ew, out, cnt);
        const int NPB = 16;
        dim3 g2((N_NODE + NPB - 1) / NPB);
        rgc_finalize<<<g2, 256, 0, stream>>>(W, b, rel_emb, cnt, out, NPB);
        return;
    }

    unsigned* hist    = (unsigned*)((char*)d_ws + OFF_HIST);
    unsigned* cursor  = (unsigned*)((char*)d_ws + OFF_CURSOR);
    unsigned* offsets = (unsigned*)((char*)d_ws + OFF_OFFS);
    unsigned* partial = (unsigned*)((char*)d_ws + OFF_PART);
    float2*   perm    = (float2*)  ((char*)d_ws + OFF_PERM);

    hipMemsetAsync(hist, 0, (size_t)N_NODE * sizeof(unsigned), stream);

    dim3 ge((N_EDGE + 255) / 256);
    rgc_hist<<<ge, 256, 0, stream>>>(node_out, hist);
    rgc_scan1<<<SCAN_TILES, 256, 0, stream>>>(hist, partial);
    rgc_scan3<<<SCAN_TILES, 256, 0, stream>>>(hist, partial, offsets, cursor);
    rgc_permute<<<ge, 256, 0, stream>>>(node_in, node_out, relation, ew, cursor, perm);

    dim3 gf((N_NODE + NPC - 1) / NPC);   // 1563
    rgc_fused<<<gf, 256, 0, stream>>>(x, W, b, rel_emb, offsets, perm, out);
}